// Round 1
// baseline (294.989 us; speedup 1.0000x reference)
//
#include <hip/hip_runtime.h>

// out[e, k, i, j] = rf[e][i] * na[sender[e]][k] * ea[e][j]
// rf[e][i] = b[i] + sum_m radial[e][m] * W[i][m]
// layout: out offset = e*512 + k*128 + i*16 + j ; duplicated at +E*512.
// One thread per float4 (16B) of combined_r: flat = e*128 + t,
//   t in [0,128): k = t>>5, i = (t>>2)&7, j4 = t&3.

__global__ void edge_embed_kernel(const int* __restrict__ edge_index,
                                  const float* __restrict__ radial,
                                  const float* __restrict__ ea,
                                  const float* __restrict__ na,
                                  const float* __restrict__ W,
                                  const float* __restrict__ b,
                                  float* __restrict__ out,
                                  long long total_chunks,   // E * 128
                                  long long half_off)       // E * 512
{
    long long idx = (long long)blockIdx.x * blockDim.x + threadIdx.x;
    const long long stride = (long long)gridDim.x * blockDim.x;

    for (; idx < total_chunks; idx += stride) {
        const int t = (int)(idx & 127);
        const long long e = idx >> 7;
        const int k  = t >> 5;
        const int i  = (t >> 2) & 7;
        const int j4 = t & 3;

        // rf[i] = b[i] + radial[e,:] . W[i,:]   (all loads L1-resident)
        const float* __restrict__ r = radial + e * 8;
        const float* __restrict__ w = W + i * 8;
        float rf = b[i];
        #pragma unroll
        for (int m = 0; m < 8; ++m) rf = fmaf(r[m], w[m], rf);

        const int s = edge_index[e];              // sender node
        const float c = rf * na[(long long)s * 4 + k];

        const float4 eav = *reinterpret_cast<const float4*>(ea + e * 16 + j4 * 4);
        float4 o;
        o.x = c * eav.x;
        o.y = c * eav.y;
        o.z = c * eav.z;
        o.w = c * eav.w;

        const long long off = e * 512 + (long long)t * 4;
        *reinterpret_cast<float4*>(out + off) = o;
        *reinterpret_cast<float4*>(out + half_off + off) = o;
    }
}

extern "C" void kernel_launch(void* const* d_in, const int* in_sizes, int n_in,
                              void* d_out, int out_size, void* d_ws, size_t ws_size,
                              hipStream_t stream) {
    const int*   edge_index = (const int*)d_in[0];   // (2, E)
    const float* radial     = (const float*)d_in[1]; // (E, 8)
    const float* ea         = (const float*)d_in[2]; // (E, 16)
    const float* na         = (const float*)d_in[3]; // (N, 4)
    const float* W          = (const float*)d_in[4]; // (8, 8)
    const float* b          = (const float*)d_in[5]; // (8,)
    float* out = (float*)d_out;

    const long long E = in_sizes[0] / 2;
    const long long total_chunks = E * 128;   // float4 chunks in combined_r
    const long long half_off     = E * 512;   // floats

    const int block = 256;
    const int grid  = 8192;                   // grid-stride, 16 iters/thread

    edge_embed_kernel<<<grid, block, 0, stream>>>(
        edge_index, radial, ea, na, W, b, out, total_chunks, half_off);
}

// Round 2
// 216.356 us; speedup vs baseline: 1.3634x; 1.3634x over previous
//
#include <hip/hip_runtime.h>

// out[e, k, i, j] = rf[e][i] * na[sender[e]][k] * ea[e][j]
// rf[e][i] = b[i] + sum_m radial[e][m] * W[i][m]
// out offset = e*512 + k*128 + i*16 + j ; duplicated at +E*512.
//
// One thread per (e, i, j4): computes rf once, loads na[s] as one float4
// (all 4 k values), one float4 of ea, then writes 4 k-chunks x 2 streams.
// flat u = e*32 + t, t in [0,32): i = t>>2, j4 = t&3.
// Store coalescing: per k-store instruction, lanes 0-31 write a contiguous
// 512B segment of edge e, lanes 32-63 of edge e+1 -> 8 full lines/instr.

__global__ void edge_embed_kernel(const int* __restrict__ edge_index,
                                  const float* __restrict__ radial,
                                  const float* __restrict__ ea,
                                  const float* __restrict__ na,
                                  const float* __restrict__ W,
                                  const float* __restrict__ b,
                                  float* __restrict__ out,
                                  long long total,      // E * 32
                                  long long half_off)   // E * 512
{
    long long u = (long long)blockIdx.x * blockDim.x + threadIdx.x;
    const long long stride = (long long)gridDim.x * blockDim.x;

    for (; u < total; u += stride) {
        const int t = (int)(u & 31);
        const long long e = u >> 5;
        const int i  = t >> 2;
        const int j4 = t & 3;

        // rf[i] = b[i] + radial[e,:] . W[i,:]  (wave-broadcast L1 hits)
        const float* __restrict__ r = radial + e * 8;
        const float* __restrict__ w = W + i * 8;
        float rf = b[i];
        #pragma unroll
        for (int m = 0; m < 8; ++m) rf = fmaf(r[m], w[m], rf);

        const int s = edge_index[e];
        const float4 na4 = *reinterpret_cast<const float4*>(na + (long long)s * 4);
        const float4 ea4 = *reinterpret_cast<const float4*>(ea + e * 16 + j4 * 4);

        const float c0 = rf * na4.x;
        const float c1 = rf * na4.y;
        const float c2 = rf * na4.z;
        const float c3 = rf * na4.w;

        const long long base = e * 512 + (long long)t * 4;  // floats

        float4 o;
        #pragma unroll
        for (int k = 0; k < 4; ++k) {
            const float c = (k == 0) ? c0 : (k == 1) ? c1 : (k == 2) ? c2 : c3;
            o.x = c * ea4.x; o.y = c * ea4.y; o.z = c * ea4.z; o.w = c * ea4.w;
            *reinterpret_cast<float4*>(out + base + k * 128) = o;
            *reinterpret_cast<float4*>(out + half_off + base + k * 128) = o;
        }
    }
}

extern "C" void kernel_launch(void* const* d_in, const int* in_sizes, int n_in,
                              void* d_out, int out_size, void* d_ws, size_t ws_size,
                              hipStream_t stream) {
    const int*   edge_index = (const int*)d_in[0];   // (2, E)
    const float* radial     = (const float*)d_in[1]; // (E, 8)
    const float* ea         = (const float*)d_in[2]; // (E, 16)
    const float* na         = (const float*)d_in[3]; // (N, 4)
    const float* W          = (const float*)d_in[4]; // (8, 8)
    const float* b          = (const float*)d_in[5]; // (8,)
    float* out = (float*)d_out;

    const long long E = in_sizes[0] / 2;
    const long long total    = E * 32;    // threads' work items
    const long long half_off = E * 512;   // floats

    const int block = 256;
    const int grid  = 8192;               // grid-stride, 4 iters/thread

    edge_embed_kernel<<<grid, block, 0, stream>>>(
        edge_index, radial, ea, na, W, b, out, total, half_off);
}

// Round 4
// 196.667 us; speedup vs baseline: 1.4999x; 1.1001x over previous
//
#include <hip/hip_runtime.h>

// out[e, k, i, j] = rf[e][i] * na[sender[e]][k] * ea[e][j]
// rf[e][i] = b[i] + sum_m radial[e][m] * W[i][m]
// out offset = e*512 + k*128 + i*16 + j ; duplicated at +E*512.
//
// One thread per (e, i, j4). Stores are non-temporal (global_store_dwordx4 nt):
// the 1 GB output is write-once, never re-read -> bypass L2 allocation.
// NOTE: __builtin_nontemporal_store needs a clang native vector type,
// not HIP's float4 wrapper class.

typedef float f32x4 __attribute__((ext_vector_type(4)));

__global__ void edge_embed_kernel(const int* __restrict__ edge_index,
                                  const float* __restrict__ radial,
                                  const float* __restrict__ ea,
                                  const float* __restrict__ na,
                                  const float* __restrict__ W,
                                  const float* __restrict__ b,
                                  float* __restrict__ out,
                                  long long total,      // E * 32
                                  long long half_off)   // E * 512
{
    long long u = (long long)blockIdx.x * blockDim.x + threadIdx.x;
    const long long stride = (long long)gridDim.x * blockDim.x;

    for (; u < total; u += stride) {
        const int t = (int)(u & 31);
        const long long e = u >> 5;
        const int i  = t >> 2;
        const int j4 = t & 3;

        // rf[i] = b[i] + radial[e,:] . W[i,:]  (wave-broadcast L1 hits)
        const float* __restrict__ r = radial + e * 8;
        const float* __restrict__ w = W + i * 8;
        float rf = b[i];
        #pragma unroll
        for (int m = 0; m < 8; ++m) rf = fmaf(r[m], w[m], rf);

        const int s = edge_index[e];
        const f32x4 na4 = *reinterpret_cast<const f32x4*>(na + (long long)s * 4);
        const f32x4 ea4 = *reinterpret_cast<const f32x4*>(ea + e * 16 + j4 * 4);

        const long long base = e * 512 + (long long)t * 4;  // floats

        #pragma unroll
        for (int k = 0; k < 4; ++k) {
            const float c = rf * na4[k];
            f32x4 o = c * ea4;
            __builtin_nontemporal_store(o, reinterpret_cast<f32x4*>(out + base + k * 128));
            __builtin_nontemporal_store(o, reinterpret_cast<f32x4*>(out + half_off + base + k * 128));
        }
    }
}

extern "C" void kernel_launch(void* const* d_in, const int* in_sizes, int n_in,
                              void* d_out, int out_size, void* d_ws, size_t ws_size,
                              hipStream_t stream) {
    const int*   edge_index = (const int*)d_in[0];   // (2, E)
    const float* radial     = (const float*)d_in[1]; // (E, 8)
    const float* ea         = (const float*)d_in[2]; // (E, 16)
    const float* na         = (const float*)d_in[3]; // (N, 4)
    const float* W          = (const float*)d_in[4]; // (8, 8)
    const float* b          = (const float*)d_in[5]; // (8,)
    float* out = (float*)d_out;

    const long long E = in_sizes[0] / 2;
    const long long total    = E * 32;    // work items
    const long long half_off = E * 512;   // floats

    const int block = 256;
    const int grid  = 8192;               // grid-stride, 4 iters/thread

    edge_embed_kernel<<<grid, block, 0, stream>>>(
        edge_index, radial, ea, na, W, b, out, total, half_off);
}